// Round 1
// baseline (2178.305 us; speedup 1.0000x reference)
//
#include <hip/hip_runtime.h>

#define Bb 64
#define Tt 2048
#define Ii 64
#define Hh 128
#define Gg 384   // 3*H
#define Oo 64

typedef _Float16 f16;

// ---------------- K1: x-projection  xg[row,g] = dot(x[row,:], W_ih[g,:]) + b_ih[g]
// 512 blocks x 384 threads; thread g holds W_ih row in registers; x rows staged in LDS.
__global__ __launch_bounds__(384) void xproj_kernel(
    const float* __restrict__ inputs, const float* __restrict__ W_ih,
    const float* __restrict__ b_ih, f16* __restrict__ xR, f16* __restrict__ xZN,
    int rowsPerBlock)
{
    __shared__ __align__(16) float xs[16 * 64];
    const int tid = threadIdx.x;

    float wi[64];
#pragma unroll
    for (int k = 0; k < 64; ++k) wi[k] = W_ih[(size_t)tid * 64 + k];
    const float bi = b_ih[tid];

    const int rowBase = blockIdx.x * rowsPerBlock;
    for (int c = 0; c < rowsPerBlock; c += 16) {
        __syncthreads();
        for (int idx = tid; idx < 16 * 64; idx += 384)
            xs[idx] = inputs[(size_t)(rowBase + c) * 64 + idx];
        __syncthreads();
#pragma unroll 4
        for (int rr = 0; rr < 16; ++rr) {
            const int row = rowBase + c + rr;
            const float4* x4 = (const float4*)&xs[rr * 64];
            float a0 = bi, a1 = 0.f, a2 = 0.f, a3 = 0.f;
#pragma unroll
            for (int i = 0; i < 16; ++i) {
                float4 v = x4[i];
                a0 = fmaf(v.x, wi[4 * i + 0], a0);
                a1 = fmaf(v.y, wi[4 * i + 1], a1);
                a2 = fmaf(v.z, wi[4 * i + 2], a2);
                a3 = fmaf(v.w, wi[4 * i + 3], a3);
            }
            const float acc = (a0 + a1) + (a2 + a3);
            if (tid < 128) xR[(size_t)row * 128 + tid] = (f16)acc;
            else           xZN[(size_t)row * 256 + (tid - 128)] = (f16)acc;
        }
    }
}

// ---------------- K2: the sequential GRU recurrence. One block per batch element.
// 384 threads: tid<128 -> r-gate, 128..255 -> z-gate, 256..383 -> n-gate + h-update.
// W_hh row per thread in registers (128 VGPR); h broadcast from LDS (b128 same-address).
__global__ __launch_bounds__(384) void gru_kernel(
    const float* __restrict__ W_hh, const float* __restrict__ b_hh,
    const f16* __restrict__ xR, const f16* __restrict__ xZN,
    float* __restrict__ latents)
{
    __shared__ __align__(16) float hf[Hh];
    __shared__ float rs[Hh];
    __shared__ float zs[Hh];

    const int tid = threadIdx.x;
    const int b   = blockIdx.x;
    const int j   = tid & 127;

    float w[Hh];
#pragma unroll
    for (int k = 0; k < Hh; ++k) w[k] = W_hh[(size_t)tid * Hh + k];
    const float bh = b_hh[tid];

    if (tid < Hh) hf[tid] = 0.f;

    const f16* xr  = xR  + (size_t)b * Tt * Hh;
    const f16* xzn = xZN + (size_t)b * Tt * (2 * Hh);
    float* lat = latents + (size_t)b * Tt * Hh;

    // prefetch t=0
    float xcur;
    if (tid < 128) xcur = (float)xr[tid];
    else           xcur = (float)xzn[tid - 128];
    __syncthreads();

    for (int t = 0; t < Tt; ++t) {
        // prefetch next step's x-projection (one full step of latency distance)
        float xnext = 0.f;
        if (t + 1 < Tt) {
            if (tid < 128) xnext = (float)xr[(size_t)(t + 1) * Hh + tid];
            else           xnext = (float)xzn[(size_t)(t + 1) * (2 * Hh) + (tid - 128)];
        }

        // phase 1: hdot[g] = b_hh[g] + sum_k h[k] * W_hh[g,k]
        float a0 = bh, a1 = 0.f, a2 = 0.f, a3 = 0.f;
        const float4* h4 = (const float4*)hf;
#pragma unroll
        for (int i = 0; i < Hh / 4; ++i) {
            float4 v = h4[i];
            a0 = fmaf(v.x, w[4 * i + 0], a0);
            a1 = fmaf(v.y, w[4 * i + 1], a1);
            a2 = fmaf(v.z, w[4 * i + 2], a2);
            a3 = fmaf(v.w, w[4 * i + 3], a3);
        }
        const float acc = (a0 + a1) + (a2 + a3);

        if (tid < 128) {
            const float p = acc + xcur;
            rs[j] = 1.f / (1.f + __expf(-p));
        } else if (tid < 256) {
            const float p = acc + xcur;
            zs[j] = 1.f / (1.f + __expf(-p));
        }
        __syncthreads();

        // phase 2: n = tanh(xn + r*hn); h' = (1-z)*n + z*h
        if (tid >= 256) {
            const float r  = rs[j];
            const float z  = zs[j];
            const float hp = hf[j];
            const float a  = xcur + r * acc;
            const float e  = __expf(2.f * a);
            const float n  = 1.f - 2.f / (e + 1.f);   // tanh, NaN-free at +inf
            const float hnew = n + z * (hp - n);
            hf[j] = hnew;
            lat[(size_t)t * Hh + j] = hnew;
        }
        __syncthreads();
        xcur = xnext;
    }
}

// ---------------- K3: out[row,o] = dot(latents[row,:], W_out[o,:]) + b_out[o]
// wave = 64 lanes = 64 outputs; W_out row per lane in registers; latents row broadcast.
__global__ __launch_bounds__(256) void outproj_kernel(
    const float* __restrict__ latents, const float* __restrict__ W_out,
    const float* __restrict__ b_out, float* __restrict__ out, int rowsPerWave)
{
    const int lane = threadIdx.x & 63;
    const int wave = threadIdx.x >> 6;

    float w[128];
#pragma unroll
    for (int k = 0; k < 128; ++k) w[k] = W_out[(size_t)lane * 128 + k];
    const float bo = b_out[lane];

    const int waveId  = blockIdx.x * 4 + wave;
    const int rowBase = waveId * rowsPerWave;

    for (int rr = 0; rr < rowsPerWave; ++rr) {
        const int row = rowBase + rr;
        const float4* l4 = (const float4*)(latents + (size_t)row * 128);
        float a0 = bo, a1 = 0.f, a2 = 0.f, a3 = 0.f;
#pragma unroll
        for (int i = 0; i < 32; ++i) {
            float4 v = l4[i];
            a0 = fmaf(v.x, w[4 * i + 0], a0);
            a1 = fmaf(v.y, w[4 * i + 1], a1);
            a2 = fmaf(v.z, w[4 * i + 2], a2);
            a3 = fmaf(v.w, w[4 * i + 3], a3);
        }
        out[(size_t)row * 64 + lane] = (a0 + a1) + (a2 + a3);
    }
}

extern "C" void kernel_launch(void* const* d_in, const int* in_sizes, int n_in,
                              void* d_out, int out_size, void* d_ws, size_t ws_size,
                              hipStream_t stream) {
    const float* inputs = (const float*)d_in[0];
    const float* W_ih   = (const float*)d_in[1];
    const float* W_hh   = (const float*)d_in[2];
    const float* b_ih   = (const float*)d_in[3];
    const float* b_hh   = (const float*)d_in[4];
    const float* W_out  = (const float*)d_in[5];
    const float* b_out  = (const float*)d_in[6];

    float* out     = (float*)d_out;
    float* latents = out + (size_t)Bb * Tt * Oo;

    // x_proj staging (f16): r-gates [B*T*128], z+n-gates [B*T*256].
    const size_t xbytes = (size_t)Bb * Tt * Gg * sizeof(f16);  // 100,663,296 B
    f16 *xR, *xZN;
    if (ws_size >= xbytes) {
        xR  = (f16*)d_ws;
        xZN = xR + (size_t)Bb * Tt * Hh;
    } else {
        // Alias into d_out: r-gates fit exactly in the output region (33,554,432 B),
        // z/n-gates exactly in the latents region (67,108,864 B). Step-t latents
        // writes only touch bytes already consumed (prefetch distance = 1 step),
        // and K3 overwrites the output region only after K2 finished reading it.
        xR  = (f16*)d_out;
        xZN = (f16*)latents;
    }

    xproj_kernel<<<512, 384, 0, stream>>>(inputs, W_ih, b_ih, xR, xZN,
                                          (Bb * Tt) / 512);
    gru_kernel<<<Bb, 384, 0, stream>>>(W_hh, b_hh, xR, xZN, latents);
    outproj_kernel<<<512, 256, 0, stream>>>(latents, W_out, b_out, out, 64);
}